// Round 20
// baseline (194.895 us; speedup 1.0000x reference)
//
#include <hip/hip_runtime.h>
#include <hip/hip_fp16.h>

#define NN 50000
#define EE 800000
#define ETOT (EE + NN)          // 850000
#define HIDD 64
#define NHEADS 4
#define FCD 160
#define OUTD 64

#define NBKT 196                // dst>>8 -> 196 buckets of 256 dst nodes
#define BSTRIDE 5120            // fixed per-bucket capacity (mean 4352)
#define CHUNK 4096
#define NEBLK ((ETOT + CHUNK - 1) / CHUNK)   // 208
#define NGB   ((NN + 63) / 64)  // 782

typedef _Float16 hf2 __attribute__((ext_vector_type(2)));

static __device__ __forceinline__ float fdot2f(unsigned a, unsigned b, float c) {
#if defined(__has_builtin)
#if __has_builtin(__builtin_amdgcn_fdot2)
    union { unsigned u; hf2 h; } ua, ub;
    ua.u = a; ub.u = b;
    return __builtin_amdgcn_fdot2(ua.h, ub.h, c, false);
#else
    __half2 ha = *(__half2*)&a, hb = *(__half2*)&b;
    float2 fa = __half22float2(ha), fb = __half22float2(hb);
    return c + fa.x * fb.x + fa.y * fb.y;
#endif
#else
    __half2 ha = *(__half2*)&a, hb = *(__half2*)&b;
    float2 fa = __half22float2(ha), fb = __half22float2(hb);
    return c + fa.x * fb.x + fa.y * fb.y;
#endif
}

// ---------------- pack W1/W2 to fp16 k-pairs + zero cursor ----------------

__global__ __launch_bounds__(256) void k_packw(const float* __restrict__ W1,
                                               const float* __restrict__ W2,
                                               unsigned* __restrict__ W1p,
                                               unsigned* __restrict__ W2p,
                                               int* __restrict__ cursor) {
    int i = blockIdx.x * 256 + threadIdx.x;
    if (blockIdx.x == 0 && threadIdx.x < NBKT) cursor[threadIdx.x] = 0;
    if (i < 32 * 160) {
        int k2 = i / 160, j = i - k2 * 160;
        __half2 p = __floats2half2_rn(W1[(2 * k2) * 160 + j], W1[(2 * k2 + 1) * 160 + j]);
        W1p[i] = *(unsigned*)&p;
    }
    if (i < 80 * 64) {
        int k2 = i / 64, j = i - k2 * 64;
        __half2 p = __floats2half2_rn(W2[(2 * k2) * 64 + j], W2[(2 * k2 + 1) * 64 + j]);
        W2p[i] = *(unsigned*)&p;
    }
}

// ---------------- CSR build: fixed-stride bucketed counting sort ----------------

__global__ __launch_bounds__(256) void k_binwrite(const int* __restrict__ ei,
                                                  int* __restrict__ cursor,
                                                  unsigned* __restrict__ binned) {
    __shared__ int hist[NBKT];
    __shared__ int sbase[NBKT];
    __shared__ int cur[NBKT];
    int t = threadIdx.x;
    for (int i = t; i < NBKT; i += 256) hist[i] = 0;
    __syncthreads();
    int base = blockIdx.x * CHUNK;
    for (int k = t; k < CHUNK; k += 256) {
        int i = base + k;
        if (i < ETOT) {
            int dst = (i < EE) ? ei[EE + i] : (i - EE);
            atomicAdd(&hist[dst >> 8], 1);
        }
    }
    __syncthreads();
    for (int b = t; b < NBKT; b += 256) {
        int c = hist[b];
        sbase[b] = b * BSTRIDE + (c ? atomicAdd(&cursor[b], c) : 0);
        cur[b] = 0;
    }
    __syncthreads();
    for (int k = t; k < CHUNK; k += 256) {
        int i = base + k;
        if (i < ETOT) {
            int src, dst;
            if (i < EE) { src = ei[i]; dst = ei[EE + i]; }
            else { src = dst = i - EE; }
            int b = dst >> 8;
            int p = atomicAdd(&cur[b], 1);
            binned[sbase[b] + p] = ((unsigned)src << 8) | (unsigned)(dst & 255);
        }
    }
}

__global__ __launch_bounds__(256) void k_csr_final(const int* __restrict__ cursor,
                                                   const unsigned* __restrict__ binned,
                                                   int* __restrict__ rowbeg,
                                                   int* __restrict__ rowend,
                                                   int* __restrict__ csrc) {
    __shared__ int hist[256];
    __shared__ int cur[256];
    __shared__ int wsum[4];
    int b = blockIdx.x;
    int t = threadIdx.x;
    int s0 = b * BSTRIDE;
    int cnt = cursor[b];
    hist[t] = 0;
    __syncthreads();
    for (int k = t; k < cnt; k += 256) {
        unsigned pr = binned[s0 + k];
        atomicAdd(&hist[pr & 255u], 1);
    }
    __syncthreads();
    int v = hist[t];
    int lane = t & 63, w = t >> 6;
    int x = v;
    #pragma unroll
    for (int off = 1; off < 64; off <<= 1) {
        int y = __shfl_up(x, off);
        if (lane >= off) x += y;
    }
    if (lane == 63) wsum[w] = x;
    __syncthreads();
    int add = 0;
    #pragma unroll
    for (int k = 0; k < 4; k++) add += (k < w) ? wsum[k] : 0;
    int excl = x + add - v;
    int n = (b << 8) + t;
    if (n < NN) {
        rowbeg[n] = s0 + excl;
        rowend[n] = s0 + excl + v;
    }
    cur[t] = s0 + excl;
    __syncthreads();
    for (int k = t; k < cnt; k += 256) {
        unsigned pr = binned[s0 + k];
        int p = atomicAdd(&cur[pr & 255u], 1);
        csrc[p] = (int)(pr >> 8);
    }
}

// ---------------- GEMM h = x@W (fp32 compute, fp16 store) + scores (layer 0) ----------------

template<int FIN>
__global__ __launch_bounds__(256) void k_gemm_scores(
        const float* __restrict__ x, const float* __restrict__ W,
        const float* __restrict__ a_src, const float* __restrict__ a_dst,
        __half* __restrict__ h, float* __restrict__ ssrc, float* __restrict__ sdst) {
    __shared__ float wl[64 * 64];       // 16 KB
    __shared__ float xt[64][68];        // 17.4 KB
    int t = threadIdx.x;
    int nb = blockIdx.x * 64;
    int qg = t & 15, ng = t >> 4;
    float acc[4][4] = {};
    const float4* wl4 = (const float4*)wl;

    #pragma unroll
    for (int p = 0; p < FIN / 64; p++) {
        if (p) __syncthreads();
        for (int i = t; i < 64 * 64 / 4; i += 256)
            ((float4*)wl)[i] = ((const float4*)W)[p * 1024 + i];
        #pragma unroll
        for (int r = 0; r < 4; r++) {
            int idx = t + r * 256;
            int node = idx & 63, kq = idx >> 6;
            int n = nb + node;
            float4 v = make_float4(0.f, 0.f, 0.f, 0.f);
            if (n < NN) v = *(const float4*)(x + (size_t)n * FIN + p * 64 + kq * 4);
            xt[kq * 4 + 0][node] = v.x;
            xt[kq * 4 + 1][node] = v.y;
            xt[kq * 4 + 2][node] = v.z;
            xt[kq * 4 + 3][node] = v.w;
        }
        __syncthreads();
        #pragma unroll 4
        for (int k = 0; k < 64; k++) {
            float4 wv = wl4[k * 16 + qg];
            float4 xv = *(const float4*)&xt[k][ng * 4];
            acc[0][0] += xv.x * wv.x; acc[0][1] += xv.x * wv.y;
            acc[0][2] += xv.x * wv.z; acc[0][3] += xv.x * wv.w;
            acc[1][0] += xv.y * wv.x; acc[1][1] += xv.y * wv.y;
            acc[1][2] += xv.y * wv.z; acc[1][3] += xv.y * wv.w;
            acc[2][0] += xv.z * wv.x; acc[2][1] += xv.z * wv.y;
            acc[2][2] += xv.z * wv.z; acc[2][3] += xv.z * wv.w;
            acc[3][0] += xv.w * wv.x; acc[3][1] += xv.w * wv.y;
            acc[3][2] += xv.w * wv.z; acc[3][3] += xv.w * wv.w;
        }
    }

    #pragma unroll
    for (int r = 0; r < 4; r++) {
        int n = nb + ng * 4 + r;
        if (n < NN) {
            union { __half2 h2[2]; uint2 u; } pk;
            pk.h2[0] = __floats2half2_rn(acc[r][0], acc[r][1]);
            pk.h2[1] = __floats2half2_rn(acc[r][2], acc[r][3]);
            *(uint2*)(h + (size_t)n * HIDD + qg * 4) = pk.u;
        }
    }

    float as0 = a_src[qg * 4 + 0], as1 = a_src[qg * 4 + 1];
    float as2 = a_src[qg * 4 + 2], as3 = a_src[qg * 4 + 3];
    float ad0 = a_dst[qg * 4 + 0], ad1 = a_dst[qg * 4 + 1];
    float ad2 = a_dst[qg * 4 + 2], ad3 = a_dst[qg * 4 + 3];
    float vs[4], vd[4];
    #pragma unroll
    for (int r = 0; r < 4; r++) {
        vs[r] = acc[r][0] * as0 + acc[r][1] * as1 + acc[r][2] * as2 + acc[r][3] * as3;
        vd[r] = acc[r][0] * ad0 + acc[r][1] * ad1 + acc[r][2] * ad2 + acc[r][3] * ad3;
        vs[r] += __shfl_xor(vs[r], 1); vs[r] += __shfl_xor(vs[r], 2);
        vd[r] += __shfl_xor(vd[r], 1); vd[r] += __shfl_xor(vd[r], 2);
    }
    if ((qg & 3) == 0) {
        int hd = qg >> 2;
        #pragma unroll
        for (int r = 0; r < 4; r++) {
            int n = nb + ng * 4 + r;
            if (n < NN) {
                ssrc[n * NHEADS + hd] = vs[r];
                sdst[n * NHEADS + hd] = vd[r];
            }
        }
    }
}

// ---------------- fused aggr(L) + gemm(L+1): act stays in LDS ----------------
// Gather: 32 edges/pass (8 per sub), 16 outstanding loads per lane.

__global__ __launch_bounds__(512) void k_aggr_gemm(
        const __half* __restrict__ h, const float* __restrict__ ssrc,
        const float* __restrict__ sdst, const int* __restrict__ rowbeg,
        const int* __restrict__ rowend, const int* __restrict__ csrc,
        const float* __restrict__ bias, const float* __restrict__ W,
        const float* __restrict__ a_src, const float* __restrict__ a_dst,
        __half* __restrict__ hout, float* __restrict__ ssrc_o,
        float* __restrict__ sdst_o) {
    __shared__ float wl[64 * 64];       // 16 KB
    __shared__ float xt[64][68];        // 17.4 KB
    int t = threadIdx.x;
    int nb = blockIdx.x * 64;

    for (int i = t; i < 64 * 64 / 4; i += 512)
        ((float4*)wl)[i] = ((const float4*)W)[i];

    {
        int wid = t >> 6, lane = t & 63;
        int sub = lane >> 4, c4 = lane & 15, hd = c4 >> 2;
        #pragma unroll 1
        for (int i = 0; i < 8; i++) {
            int nl = wid * 8 + i;
            int n = nb + nl;
            float4 acc = make_float4(0.f, 0.f, 0.f, 0.f);
            float z = 0.f;
            if (n < NN) {
                int beg = rowbeg[n], end = rowend[n];
                float sdh = sdst[n * NHEADS + hd];
                for (int cb = beg; cb < end; cb += 64) {
                    int m = min(64, end - cb);
                    int s_all = (cb + lane < end) ? csrc[cb + lane] : 0;
                    for (int pb = 0; pb < m; pb += 32) {
                        float ssv[8]; uint2 hr[8];
                        #pragma unroll
                        for (int o = 0; o < 8; o++) {
                            int jj = pb + sub * 8 + o;
                            int s = __shfl(s_all, jj);
                            if (jj < m) {
                                ssv[o] = ssrc[s * NHEADS + hd];
                                hr[o] = *(const uint2*)(h + (size_t)s * HIDD + c4 * 4);
                            }
                        }
                        #pragma unroll
                        for (int o = 0; o < 8; o++) {
                            int jj = pb + sub * 8 + o;
                            if (jj < m) {
                                float eh = ssv[o] + sdh;
                                eh = eh > 0.f ? eh : 0.2f * eh;
                                float w = __expf(eh);
                                float2 lo = __half22float2(*(__half2*)&hr[o].x);
                                float2 hi = __half22float2(*(__half2*)&hr[o].y);
                                acc.x += lo.x * w; acc.y += lo.y * w;
                                acc.z += hi.x * w; acc.w += hi.y * w;
                                z += w;
                            }
                        }
                    }
                }
            }
            acc.x += __shfl_xor(acc.x, 16); acc.y += __shfl_xor(acc.y, 16);
            acc.z += __shfl_xor(acc.z, 16); acc.w += __shfl_xor(acc.w, 16);
            z += __shfl_xor(z, 16);
            acc.x += __shfl_xor(acc.x, 32); acc.y += __shfl_xor(acc.y, 32);
            acc.z += __shfl_xor(acc.z, 32); acc.w += __shfl_xor(acc.w, 32);
            z += __shfl_xor(z, 32);
            if (sub == 0) {
                float inv_z = 1.0f / (z + 1e-16f);
                float4 bv = *(const float4*)(bias + c4 * 4);
                float v0 = acc.x * inv_z + bv.x; v0 = v0 > 0.f ? v0 : 0.f;
                float v1 = acc.y * inv_z + bv.y; v1 = v1 > 0.f ? v1 : 0.f;
                float v2 = acc.z * inv_z + bv.z; v2 = v2 > 0.f ? v2 : 0.f;
                float v3 = acc.w * inv_z + bv.w; v3 = v3 > 0.f ? v3 : 0.f;
                if (n >= NN) { v0 = v1 = v2 = v3 = 0.f; }
                xt[c4 * 4 + 0][nl] = v0;
                xt[c4 * 4 + 1][nl] = v1;
                xt[c4 * 4 + 2][nl] = v2;
                xt[c4 * 4 + 3][nl] = v3;
            }
        }
    }
    __syncthreads();

    {
        int qg = t & 15, ng = t >> 4;
        float acc[2][4] = {};
        const float4* wl4 = (const float4*)wl;
        #pragma unroll 4
        for (int k = 0; k < 64; k++) {
            float4 wv = wl4[k * 16 + qg];
            float2 xv = *(const float2*)&xt[k][ng * 2];
            acc[0][0] += xv.x * wv.x; acc[0][1] += xv.x * wv.y;
            acc[0][2] += xv.x * wv.z; acc[0][3] += xv.x * wv.w;
            acc[1][0] += xv.y * wv.x; acc[1][1] += xv.y * wv.y;
            acc[1][2] += xv.y * wv.z; acc[1][3] += xv.y * wv.w;
        }
        #pragma unroll
        for (int r = 0; r < 2; r++) {
            int n = nb + ng * 2 + r;
            if (n < NN) {
                union { __half2 h2[2]; uint2 u; } pk;
                pk.h2[0] = __floats2half2_rn(acc[r][0], acc[r][1]);
                pk.h2[1] = __floats2half2_rn(acc[r][2], acc[r][3]);
                *(uint2*)(hout + (size_t)n * HIDD + qg * 4) = pk.u;
            }
        }
        float as0 = a_src[qg * 4 + 0], as1 = a_src[qg * 4 + 1];
        float as2 = a_src[qg * 4 + 2], as3 = a_src[qg * 4 + 3];
        float ad0 = a_dst[qg * 4 + 0], ad1 = a_dst[qg * 4 + 1];
        float ad2 = a_dst[qg * 4 + 2], ad3 = a_dst[qg * 4 + 3];
        float vs[2], vd[2];
        #pragma unroll
        for (int r = 0; r < 2; r++) {
            vs[r] = acc[r][0] * as0 + acc[r][1] * as1 + acc[r][2] * as2 + acc[r][3] * as3;
            vd[r] = acc[r][0] * ad0 + acc[r][1] * ad1 + acc[r][2] * ad2 + acc[r][3] * ad3;
            vs[r] += __shfl_xor(vs[r], 1); vs[r] += __shfl_xor(vs[r], 2);
            vd[r] += __shfl_xor(vd[r], 1); vd[r] += __shfl_xor(vd[r], 2);
        }
        if ((qg & 3) == 0) {
            int hd = qg >> 2;
            #pragma unroll
            for (int r = 0; r < 2; r++) {
                int n = nb + ng * 2 + r;
                if (n < NN) {
                    ssrc_o[n * NHEADS + hd] = vs[r];
                    sdst_o[n * NHEADS + hd] = vd[r];
                }
            }
        }
    }
}

// ---------------- final aggregation (layer 2 output -> act fp16 for FC) ----------------

__global__ __launch_bounds__(256) void k_aggr(
        const __half* __restrict__ h, const float* __restrict__ ssrc,
        const float* __restrict__ sdst, const int* __restrict__ rowbeg,
        const int* __restrict__ rowend,
        const int* __restrict__ csrc, const float* __restrict__ bias,
        __half* __restrict__ out) {
    int wid  = threadIdx.x >> 6;
    int lane = threadIdx.x & 63;
    int n = blockIdx.x * 4 + wid;
    int sub = lane >> 4;
    int c4  = lane & 15;
    int hd  = c4 >> 2;
    int beg = rowbeg[n], end = rowend[n];
    float sdh = sdst[n * NHEADS + hd];

    float4 acc = make_float4(0.f, 0.f, 0.f, 0.f);
    float z = 0.f;
    for (int cb = beg; cb < end; cb += 64) {
        int m = min(64, end - cb);
        int s_all = (cb + lane < end) ? csrc[cb + lane] : 0;
        for (int pb = 0; pb < m; pb += 32) {
            float ssv[8]; uint2 hr[8];
            #pragma unroll
            for (int o = 0; o < 8; o++) {
                int jj = pb + sub * 8 + o;
                int s = __shfl(s_all, jj);
                if (jj < m) {
                    ssv[o] = ssrc[s * NHEADS + hd];
                    hr[o] = *(const uint2*)(h + (size_t)s * HIDD + c4 * 4);
                }
            }
            #pragma unroll
            for (int o = 0; o < 8; o++) {
                int jj = pb + sub * 8 + o;
                if (jj < m) {
                    float eh = ssv[o] + sdh;
                    eh = eh > 0.f ? eh : 0.2f * eh;
                    float w = __expf(eh);
                    float2 lo = __half22float2(*(__half2*)&hr[o].x);
                    float2 hi = __half22float2(*(__half2*)&hr[o].y);
                    acc.x += lo.x * w; acc.y += lo.y * w;
                    acc.z += hi.x * w; acc.w += hi.y * w;
                    z += w;
                }
            }
        }
    }
    acc.x += __shfl_xor(acc.x, 16); acc.y += __shfl_xor(acc.y, 16);
    acc.z += __shfl_xor(acc.z, 16); acc.w += __shfl_xor(acc.w, 16);
    z += __shfl_xor(z, 16);
    acc.x += __shfl_xor(acc.x, 32); acc.y += __shfl_xor(acc.y, 32);
    acc.z += __shfl_xor(acc.z, 32); acc.w += __shfl_xor(acc.w, 32);
    z += __shfl_xor(z, 32);

    if (sub == 0) {
        float inv_z = 1.0f / (z + 1e-16f);
        float4 bv = *(const float4*)(bias + c4 * 4);
        float v0 = acc.x * inv_z + bv.x; v0 = v0 > 0.f ? v0 : 0.f;
        float v1 = acc.y * inv_z + bv.y; v1 = v1 > 0.f ? v1 : 0.f;
        float v2 = acc.z * inv_z + bv.z; v2 = v2 > 0.f ? v2 : 0.f;
        float v3 = acc.w * inv_z + bv.w; v3 = v3 > 0.f ? v3 : 0.f;
        union { __half2 h2[2]; uint2 u; } pk;
        pk.h2[0] = __floats2half2_rn(v0, v1);
        pk.h2[1] = __floats2half2_rn(v2, v3);
        *(uint2*)(out + (size_t)n * HIDD + c4 * 4) = pk.u;
    }
}

// ---------------- fused FC head via fdot2: 64-node tile ----------------

__global__ __launch_bounds__(256) void k_fc_fused(const __half* __restrict__ x,
        const unsigned* __restrict__ W1p, const float* __restrict__ b1,
        const unsigned* __restrict__ W2p, const float* __restrict__ b2,
        float* __restrict__ out) {
    __shared__ unsigned wl[5120];       // 20 KB
    __shared__ unsigned xt2[32][68];    // 8.7 KB
    __shared__ unsigned y2[80][68];     // 21.76 KB
    int t = threadIdx.x;
    int nb = blockIdx.x * 64;
    const uint4* wl4 = (const uint4*)wl;

    for (int i = t; i < 5120 / 4; i += 256)
        ((uint4*)wl)[i] = ((const uint4*)W1p)[i];
    #pragma unroll
    for (int r = 0; r < 4; r++) {
        int idx = t + r * 256;
        int node = idx & 63, kq = idx >> 6;
        int n = nb + node;
        uint2 v = make_uint2(0u, 0u);
        if (n < NN) v = ((const uint2*)(x + (size_t)n * 64))[kq];
        xt2[kq * 2 + 0][node] = v.x;
        xt2[kq * 2 + 1][node] = v.y;
    }
    __syncthreads();

    {
        int qg = t & 7, ng = t >> 3;
        float acc[2][5][4] = {};
        #pragma unroll 2
        for (int k2 = 0; k2 < 32; k2++) {
            uint2 xv = *(const uint2*)&xt2[k2][ng * 2];
            #pragma unroll
            for (int i = 0; i < 5; i++) {
                uint4 wv = wl4[k2 * 40 + qg + 8 * i];
                acc[0][i][0] = fdot2f(xv.x, wv.x, acc[0][i][0]);
                acc[0][i][1] = fdot2f(xv.x, wv.y, acc[0][i][1]);
                acc[0][i][2] = fdot2f(xv.x, wv.z, acc[0][i][2]);
                acc[0][i][3] = fdot2f(xv.x, wv.w, acc[0][i][3]);
                acc[1][i][0] = fdot2f(xv.y, wv.x, acc[1][i][0]);
                acc[1][i][1] = fdot2f(xv.y, wv.y, acc[1][i][1]);
                acc[1][i][2] = fdot2f(xv.y, wv.z, acc[1][i][2]);
                acc[1][i][3] = fdot2f(xv.y, wv.w, acc[1][i][3]);
            }
        }
        #pragma unroll
        for (int i = 0; i < 5; i++) {
            int j0 = (qg + 8 * i) * 4;
            float4 bv = *(const float4*)(b1 + j0);
            #pragma unroll
            for (int r = 0; r < 2; r++) {
                int node = ng * 2 + r;
                float v0 = acc[r][i][0] + bv.x; v0 = v0 > 0.f ? v0 : 0.f;
                float v1 = acc[r][i][1] + bv.y; v1 = v1 > 0.f ? v1 : 0.f;
                float v2 = acc[r][i][2] + bv.z; v2 = v2 > 0.f ? v2 : 0.f;
                float v3 = acc[r][i][3] + bv.w; v3 = v3 > 0.f ? v3 : 0.f;
                __half2 p0 = __floats2half2_rn(v0, v1);
                __half2 p1 = __floats2half2_rn(v2, v3);
                y2[(qg + 8 * i) * 2 + 0][node] = *(unsigned*)&p0;
                y2[(qg + 8 * i) * 2 + 1][node] = *(unsigned*)&p1;
            }
        }
    }
    __syncthreads();

    for (int i = t; i < 5120 / 4; i += 256)
        ((uint4*)wl)[i] = ((const uint4*)W2p)[i];
    __syncthreads();

    {
        int qg = t & 15, ng = t >> 4;
        float acc[4][4] = {};
        #pragma unroll 2
        for (int k2 = 0; k2 < 80; k2++) {
            uint4 wv = wl4[k2 * 16 + qg];
            uint4 yv = *(const uint4*)&y2[k2][ng * 4];
            acc[0][0] = fdot2f(yv.x, wv.x, acc[0][0]);
            acc[0][1] = fdot2f(yv.x, wv.y, acc[0][1]);
            acc[0][2] = fdot2f(yv.x, wv.z, acc[0][2]);
            acc[0][3] = fdot2f(yv.x, wv.w, acc[0][3]);
            acc[1][0] = fdot2f(yv.y, wv.x, acc[1][0]);
            acc[1][1] = fdot2f(yv.y, wv.y, acc[1][1]);
            acc[1][2] = fdot2f(yv.y, wv.z, acc[1][2]);
            acc[1][3] = fdot2f(yv.y, wv.w, acc[1][3]);
            acc[2][0] = fdot2f(yv.z, wv.x, acc[2][0]);
            acc[2][1] = fdot2f(yv.z, wv.y, acc[2][1]);
            acc[2][2] = fdot2f(yv.z, wv.z, acc[2][2]);
            acc[2][3] = fdot2f(yv.z, wv.w, acc[2][3]);
            acc[3][0] = fdot2f(yv.w, wv.x, acc[3][0]);
            acc[3][1] = fdot2f(yv.w, wv.y, acc[3][1]);
            acc[3][2] = fdot2f(yv.w, wv.z, acc[3][2]);
            acc[3][3] = fdot2f(yv.w, wv.w, acc[3][3]);
        }
        int j0 = qg * 4;
        float4 bv = *(const float4*)(b2 + j0);
        #pragma unroll
        for (int r = 0; r < 4; r++) {
            int n = nb + ng * 4 + r;
            if (n < NN) {
                float4 o;
                o.x = acc[r][0] + bv.x; o.y = acc[r][1] + bv.y;
                o.z = acc[r][2] + bv.z; o.w = acc[r][3] + bv.w;
                *(float4*)(out + (size_t)n * 64 + j0) = o;
            }
        }
    }
}

// ---------------- launch ----------------

extern "C" void kernel_launch(void* const* d_in, const int* in_sizes, int n_in,
                              void* d_out, int out_size, void* d_ws, size_t ws_size,
                              hipStream_t stream) {
    const float* x   = (const float*)d_in[0];
    const int*   ei  = (const int*)d_in[1];
    const float* W0  = (const float*)d_in[2];
    const float* as0 = (const float*)d_in[3];
    const float* ad0 = (const float*)d_in[4];
    const float* b0  = (const float*)d_in[5];
    const float* W1  = (const float*)d_in[6];
    const float* as1 = (const float*)d_in[7];
    const float* ad1 = (const float*)d_in[8];
    const float* b1  = (const float*)d_in[9];
    const float* W2  = (const float*)d_in[10];
    const float* as2 = (const float*)d_in[11];
    const float* ad2 = (const float*)d_in[12];
    const float* b2  = (const float*)d_in[13];
    const float* fw1 = (const float*)d_in[14];
    const float* fb1 = (const float*)d_in[15];
    const float* fw2 = (const float*)d_in[16];
    const float* fb2 = (const float*)d_in[17];

    float* ws = (float*)d_ws;
    __half* hA  = (__half*)ws;                       // N*64 halves = N*32 floats
    __half* hB  = (__half*)(ws + (size_t)NN * 32);   // N*32 floats
    float* sAsrc = ws + (size_t)NN * 64;             // N*4
    float* sAdst = sAsrc + (size_t)NN * NHEADS;      // N*4
    float* sBsrc = sAdst + (size_t)NN * NHEADS;      // N*4
    float* sBdst = sBsrc + (size_t)NN * NHEADS;      // N*4
    float* actf  = sBdst + (size_t)NN * NHEADS;      // N*32 floats (fp16 act)
    __half* act  = (__half*)actf;
    float* scr   = actf + (size_t)NN * 32;           // CSR scratch region
    unsigned* binned = (unsigned*)scr;               // NBKT*BSTRIDE ~1.0M
    int*   csrc   = (int*)scr + 1100000;             // NBKT*BSTRIDE ~1.0M
    int*   rowbeg = (int*)scr + 2200000;             // NN
    int*   rowend = (int*)scr + 2300000;             // NN
    int*   cursor = (int*)scr + 2400000;             // NBKT
    unsigned* W1p = (unsigned*)scr + 2410000;        // 5120
    unsigned* W2p = (unsigned*)scr + 2420000;        // 5120

    k_packw<<<20, 256, 0, stream>>>(fw1, fw2, W1p, W2p, cursor);
    k_binwrite<<<NEBLK, 256, 0, stream>>>(ei, cursor, binned);
    k_csr_final<<<NBKT, 256, 0, stream>>>(cursor, binned, rowbeg, rowend, csrc);

    // layer 0 GEMM: x @ W0 -> hA, sA
    k_gemm_scores<128><<<NGB, 256, 0, stream>>>(x, W0, as0, ad0, hA, sAsrc, sAdst);
    // fused: aggr(layer0) + gemm(layer1) -> hB, sB
    k_aggr_gemm<<<NGB, 512, 0, stream>>>(hA, sAsrc, sAdst, rowbeg, rowend, csrc,
                                         b0, W1, as1, ad1, hB, sBsrc, sBdst);
    // fused: aggr(layer1) + gemm(layer2) -> hA, sA
    k_aggr_gemm<<<NGB, 512, 0, stream>>>(hB, sBsrc, sBdst, rowbeg, rowend, csrc,
                                         b1, W2, as2, ad2, hA, sAsrc, sAdst);
    // final aggregation -> act (fp16)
    k_aggr<<<NN / 4, 256, 0, stream>>>(hA, sAsrc, sAdst, rowbeg, rowend, csrc, b2, act);

    // fused FC head (fdot2, packed fp16 weights)
    k_fc_fused<<<NGB, 256, 0, stream>>>(act, W1p, fb1, W2p, fb2, (float*)d_out);
}

// Round 21
// 187.223 us; speedup vs baseline: 1.0410x; 1.0410x over previous
//
#include <hip/hip_runtime.h>
#include <hip/hip_fp16.h>

#define NN 50000
#define EE 800000
#define ETOT (EE + NN)          // 850000
#define HIDD 64
#define NHEADS 4
#define FCD 160
#define OUTD 64

#define NBKT 196                // dst>>8 -> 196 buckets of 256 dst nodes
#define BSTRIDE 5120            // fixed per-bucket capacity (mean 4352)
#define CHUNK 4096
#define NEBLK ((ETOT + CHUNK - 1) / CHUNK)   // 208
#define NGB   ((NN + 63) / 64)  // 782

typedef _Float16 hf2 __attribute__((ext_vector_type(2)));

static __device__ __forceinline__ float fdot2f(unsigned a, unsigned b, float c) {
#if defined(__has_builtin)
#if __has_builtin(__builtin_amdgcn_fdot2)
    union { unsigned u; hf2 h; } ua, ub;
    ua.u = a; ub.u = b;
    return __builtin_amdgcn_fdot2(ua.h, ub.h, c, false);
#else
    __half2 ha = *(__half2*)&a, hb = *(__half2*)&b;
    float2 fa = __half22float2(ha), fb = __half22float2(hb);
    return c + fa.x * fb.x + fa.y * fb.y;
#endif
#else
    __half2 ha = *(__half2*)&a, hb = *(__half2*)&b;
    float2 fa = __half22float2(ha), fb = __half22float2(hb);
    return c + fa.x * fb.x + fa.y * fb.y;
#endif
}

// ---------------- pack W1/W2 to fp16 k-pairs + zero cursor ----------------

__global__ __launch_bounds__(256) void k_packw(const float* __restrict__ W1,
                                               const float* __restrict__ W2,
                                               unsigned* __restrict__ W1p,
                                               unsigned* __restrict__ W2p,
                                               int* __restrict__ cursor) {
    int i = blockIdx.x * 256 + threadIdx.x;
    if (blockIdx.x == 0 && threadIdx.x < NBKT) cursor[threadIdx.x] = 0;
    if (i < 32 * 160) {
        int k2 = i / 160, j = i - k2 * 160;
        __half2 p = __floats2half2_rn(W1[(2 * k2) * 160 + j], W1[(2 * k2 + 1) * 160 + j]);
        W1p[i] = *(unsigned*)&p;
    }
    if (i < 80 * 64) {
        int k2 = i / 64, j = i - k2 * 64;
        __half2 p = __floats2half2_rn(W2[(2 * k2) * 64 + j], W2[(2 * k2 + 1) * 64 + j]);
        W2p[i] = *(unsigned*)&p;
    }
}

// ---------------- CSR build: fixed-stride bucketed counting sort ----------------

__global__ __launch_bounds__(256) void k_binwrite(const int* __restrict__ ei,
                                                  int* __restrict__ cursor,
                                                  unsigned* __restrict__ binned) {
    __shared__ int hist[NBKT];
    __shared__ int sbase[NBKT];
    __shared__ int cur[NBKT];
    int t = threadIdx.x;
    for (int i = t; i < NBKT; i += 256) hist[i] = 0;
    __syncthreads();
    int base = blockIdx.x * CHUNK;
    for (int k = t; k < CHUNK; k += 256) {
        int i = base + k;
        if (i < ETOT) {
            int dst = (i < EE) ? ei[EE + i] : (i - EE);
            atomicAdd(&hist[dst >> 8], 1);
        }
    }
    __syncthreads();
    for (int b = t; b < NBKT; b += 256) {
        int c = hist[b];
        sbase[b] = b * BSTRIDE + (c ? atomicAdd(&cursor[b], c) : 0);
        cur[b] = 0;
    }
    __syncthreads();
    for (int k = t; k < CHUNK; k += 256) {
        int i = base + k;
        if (i < ETOT) {
            int src, dst;
            if (i < EE) { src = ei[i]; dst = ei[EE + i]; }
            else { src = dst = i - EE; }
            int b = dst >> 8;
            int p = atomicAdd(&cur[b], 1);
            binned[sbase[b] + p] = ((unsigned)src << 8) | (unsigned)(dst & 255);
        }
    }
}

__global__ __launch_bounds__(256) void k_csr_final(const int* __restrict__ cursor,
                                                   const unsigned* __restrict__ binned,
                                                   int* __restrict__ rowbeg,
                                                   int* __restrict__ rowend,
                                                   int* __restrict__ csrc) {
    __shared__ int hist[256];
    __shared__ int cur[256];
    __shared__ int wsum[4];
    int b = blockIdx.x;
    int t = threadIdx.x;
    int s0 = b * BSTRIDE;
    int cnt = cursor[b];
    hist[t] = 0;
    __syncthreads();
    for (int k = t; k < cnt; k += 256) {
        unsigned pr = binned[s0 + k];
        atomicAdd(&hist[pr & 255u], 1);
    }
    __syncthreads();
    int v = hist[t];
    int lane = t & 63, w = t >> 6;
    int x = v;
    #pragma unroll
    for (int off = 1; off < 64; off <<= 1) {
        int y = __shfl_up(x, off);
        if (lane >= off) x += y;
    }
    if (lane == 63) wsum[w] = x;
    __syncthreads();
    int add = 0;
    #pragma unroll
    for (int k = 0; k < 4; k++) add += (k < w) ? wsum[k] : 0;
    int excl = x + add - v;
    int n = (b << 8) + t;
    if (n < NN) {
        rowbeg[n] = s0 + excl;
        rowend[n] = s0 + excl + v;
    }
    cur[t] = s0 + excl;
    __syncthreads();
    for (int k = t; k < cnt; k += 256) {
        unsigned pr = binned[s0 + k];
        int p = atomicAdd(&cur[pr & 255u], 1);
        csrc[p] = (int)(pr >> 8);
    }
}

// ---------------- GEMM h = x@W (fp32 compute, fp16 store) + scores (layer 0) ----------------

template<int FIN>
__global__ __launch_bounds__(256) void k_gemm_scores(
        const float* __restrict__ x, const float* __restrict__ W,
        const float* __restrict__ a_src, const float* __restrict__ a_dst,
        __half* __restrict__ h, float* __restrict__ ssrc, float* __restrict__ sdst) {
    __shared__ float wl[64 * 64];       // 16 KB
    __shared__ float xt[64][68];        // 17.4 KB
    int t = threadIdx.x;
    int nb = blockIdx.x * 64;
    int qg = t & 15, ng = t >> 4;
    float acc[4][4] = {};
    const float4* wl4 = (const float4*)wl;

    #pragma unroll
    for (int p = 0; p < FIN / 64; p++) {
        if (p) __syncthreads();
        for (int i = t; i < 64 * 64 / 4; i += 256)
            ((float4*)wl)[i] = ((const float4*)W)[p * 1024 + i];
        #pragma unroll
        for (int r = 0; r < 4; r++) {
            int idx = t + r * 256;
            int node = idx & 63, kq = idx >> 6;
            int n = nb + node;
            float4 v = make_float4(0.f, 0.f, 0.f, 0.f);
            if (n < NN) v = *(const float4*)(x + (size_t)n * FIN + p * 64 + kq * 4);
            xt[kq * 4 + 0][node] = v.x;
            xt[kq * 4 + 1][node] = v.y;
            xt[kq * 4 + 2][node] = v.z;
            xt[kq * 4 + 3][node] = v.w;
        }
        __syncthreads();
        #pragma unroll 4
        for (int k = 0; k < 64; k++) {
            float4 wv = wl4[k * 16 + qg];
            float4 xv = *(const float4*)&xt[k][ng * 4];
            acc[0][0] += xv.x * wv.x; acc[0][1] += xv.x * wv.y;
            acc[0][2] += xv.x * wv.z; acc[0][3] += xv.x * wv.w;
            acc[1][0] += xv.y * wv.x; acc[1][1] += xv.y * wv.y;
            acc[1][2] += xv.y * wv.z; acc[1][3] += xv.y * wv.w;
            acc[2][0] += xv.z * wv.x; acc[2][1] += xv.z * wv.y;
            acc[2][2] += xv.z * wv.z; acc[2][3] += xv.z * wv.w;
            acc[3][0] += xv.w * wv.x; acc[3][1] += xv.w * wv.y;
            acc[3][2] += xv.w * wv.z; acc[3][3] += xv.w * wv.w;
        }
    }

    #pragma unroll
    for (int r = 0; r < 4; r++) {
        int n = nb + ng * 4 + r;
        if (n < NN) {
            union { __half2 h2[2]; uint2 u; } pk;
            pk.h2[0] = __floats2half2_rn(acc[r][0], acc[r][1]);
            pk.h2[1] = __floats2half2_rn(acc[r][2], acc[r][3]);
            *(uint2*)(h + (size_t)n * HIDD + qg * 4) = pk.u;
        }
    }

    float as0 = a_src[qg * 4 + 0], as1 = a_src[qg * 4 + 1];
    float as2 = a_src[qg * 4 + 2], as3 = a_src[qg * 4 + 3];
    float ad0 = a_dst[qg * 4 + 0], ad1 = a_dst[qg * 4 + 1];
    float ad2 = a_dst[qg * 4 + 2], ad3 = a_dst[qg * 4 + 3];
    float vs[4], vd[4];
    #pragma unroll
    for (int r = 0; r < 4; r++) {
        vs[r] = acc[r][0] * as0 + acc[r][1] * as1 + acc[r][2] * as2 + acc[r][3] * as3;
        vd[r] = acc[r][0] * ad0 + acc[r][1] * ad1 + acc[r][2] * ad2 + acc[r][3] * ad3;
        vs[r] += __shfl_xor(vs[r], 1); vs[r] += __shfl_xor(vs[r], 2);
        vd[r] += __shfl_xor(vd[r], 1); vd[r] += __shfl_xor(vd[r], 2);
    }
    if ((qg & 3) == 0) {
        int hd = qg >> 2;
        #pragma unroll
        for (int r = 0; r < 4; r++) {
            int n = nb + ng * 4 + r;
            if (n < NN) {
                ssrc[n * NHEADS + hd] = vs[r];
                sdst[n * NHEADS + hd] = vd[r];
            }
        }
    }
}

// ---------------- fused aggr(L) + gemm(L+1): act stays in LDS ----------------
// Gather: 16 edges/pass (4 per sub), 8 outstanding loads per lane — measured optimum.

__global__ __launch_bounds__(512) void k_aggr_gemm(
        const __half* __restrict__ h, const float* __restrict__ ssrc,
        const float* __restrict__ sdst, const int* __restrict__ rowbeg,
        const int* __restrict__ rowend, const int* __restrict__ csrc,
        const float* __restrict__ bias, const float* __restrict__ W,
        const float* __restrict__ a_src, const float* __restrict__ a_dst,
        __half* __restrict__ hout, float* __restrict__ ssrc_o,
        float* __restrict__ sdst_o) {
    __shared__ float wl[64 * 64];       // 16 KB
    __shared__ float xt[64][68];        // 17.4 KB
    int t = threadIdx.x;
    int nb = blockIdx.x * 64;

    for (int i = t; i < 64 * 64 / 4; i += 512)
        ((float4*)wl)[i] = ((const float4*)W)[i];

    {
        int wid = t >> 6, lane = t & 63;
        int sub = lane >> 4, c4 = lane & 15, hd = c4 >> 2;
        #pragma unroll 1
        for (int i = 0; i < 8; i++) {
            int nl = wid * 8 + i;
            int n = nb + nl;
            float4 acc = make_float4(0.f, 0.f, 0.f, 0.f);
            float z = 0.f;
            if (n < NN) {
                int beg = rowbeg[n], end = rowend[n];
                float sdh = sdst[n * NHEADS + hd];
                for (int cb = beg; cb < end; cb += 64) {
                    int m = min(64, end - cb);
                    int s_all = (cb + lane < end) ? csrc[cb + lane] : 0;
                    for (int pb = 0; pb < m; pb += 16) {
                        float ssv[4]; uint2 hr[4];
                        #pragma unroll
                        for (int o = 0; o < 4; o++) {
                            int jj = pb + sub * 4 + o;
                            int s = __shfl(s_all, jj);
                            if (jj < m) {
                                ssv[o] = ssrc[s * NHEADS + hd];
                                hr[o] = *(const uint2*)(h + (size_t)s * HIDD + c4 * 4);
                            }
                        }
                        #pragma unroll
                        for (int o = 0; o < 4; o++) {
                            int jj = pb + sub * 4 + o;
                            if (jj < m) {
                                float eh = ssv[o] + sdh;
                                eh = eh > 0.f ? eh : 0.2f * eh;
                                float w = __expf(eh);
                                float2 lo = __half22float2(*(__half2*)&hr[o].x);
                                float2 hi = __half22float2(*(__half2*)&hr[o].y);
                                acc.x += lo.x * w; acc.y += lo.y * w;
                                acc.z += hi.x * w; acc.w += hi.y * w;
                                z += w;
                            }
                        }
                    }
                }
            }
            acc.x += __shfl_xor(acc.x, 16); acc.y += __shfl_xor(acc.y, 16);
            acc.z += __shfl_xor(acc.z, 16); acc.w += __shfl_xor(acc.w, 16);
            z += __shfl_xor(z, 16);
            acc.x += __shfl_xor(acc.x, 32); acc.y += __shfl_xor(acc.y, 32);
            acc.z += __shfl_xor(acc.z, 32); acc.w += __shfl_xor(acc.w, 32);
            z += __shfl_xor(z, 32);
            if (sub == 0) {
                float inv_z = 1.0f / (z + 1e-16f);
                float4 bv = *(const float4*)(bias + c4 * 4);
                float v0 = acc.x * inv_z + bv.x; v0 = v0 > 0.f ? v0 : 0.f;
                float v1 = acc.y * inv_z + bv.y; v1 = v1 > 0.f ? v1 : 0.f;
                float v2 = acc.z * inv_z + bv.z; v2 = v2 > 0.f ? v2 : 0.f;
                float v3 = acc.w * inv_z + bv.w; v3 = v3 > 0.f ? v3 : 0.f;
                if (n >= NN) { v0 = v1 = v2 = v3 = 0.f; }
                xt[c4 * 4 + 0][nl] = v0;
                xt[c4 * 4 + 1][nl] = v1;
                xt[c4 * 4 + 2][nl] = v2;
                xt[c4 * 4 + 3][nl] = v3;
            }
        }
    }
    __syncthreads();

    {
        int qg = t & 15, ng = t >> 4;
        float acc[2][4] = {};
        const float4* wl4 = (const float4*)wl;
        #pragma unroll 4
        for (int k = 0; k < 64; k++) {
            float4 wv = wl4[k * 16 + qg];
            float2 xv = *(const float2*)&xt[k][ng * 2];
            acc[0][0] += xv.x * wv.x; acc[0][1] += xv.x * wv.y;
            acc[0][2] += xv.x * wv.z; acc[0][3] += xv.x * wv.w;
            acc[1][0] += xv.y * wv.x; acc[1][1] += xv.y * wv.y;
            acc[1][2] += xv.y * wv.z; acc[1][3] += xv.y * wv.w;
        }
        #pragma unroll
        for (int r = 0; r < 2; r++) {
            int n = nb + ng * 2 + r;
            if (n < NN) {
                union { __half2 h2[2]; uint2 u; } pk;
                pk.h2[0] = __floats2half2_rn(acc[r][0], acc[r][1]);
                pk.h2[1] = __floats2half2_rn(acc[r][2], acc[r][3]);
                *(uint2*)(hout + (size_t)n * HIDD + qg * 4) = pk.u;
            }
        }
        float as0 = a_src[qg * 4 + 0], as1 = a_src[qg * 4 + 1];
        float as2 = a_src[qg * 4 + 2], as3 = a_src[qg * 4 + 3];
        float ad0 = a_dst[qg * 4 + 0], ad1 = a_dst[qg * 4 + 1];
        float ad2 = a_dst[qg * 4 + 2], ad3 = a_dst[qg * 4 + 3];
        float vs[2], vd[2];
        #pragma unroll
        for (int r = 0; r < 2; r++) {
            vs[r] = acc[r][0] * as0 + acc[r][1] * as1 + acc[r][2] * as2 + acc[r][3] * as3;
            vd[r] = acc[r][0] * ad0 + acc[r][1] * ad1 + acc[r][2] * ad2 + acc[r][3] * ad3;
            vs[r] += __shfl_xor(vs[r], 1); vs[r] += __shfl_xor(vs[r], 2);
            vd[r] += __shfl_xor(vd[r], 1); vd[r] += __shfl_xor(vd[r], 2);
        }
        if ((qg & 3) == 0) {
            int hd = qg >> 2;
            #pragma unroll
            for (int r = 0; r < 2; r++) {
                int n = nb + ng * 2 + r;
                if (n < NN) {
                    ssrc_o[n * NHEADS + hd] = vs[r];
                    sdst_o[n * NHEADS + hd] = vd[r];
                }
            }
        }
    }
}

// ---------------- final aggregation (layer 2 output -> act fp16 for FC) ----------------

__global__ __launch_bounds__(256) void k_aggr(
        const __half* __restrict__ h, const float* __restrict__ ssrc,
        const float* __restrict__ sdst, const int* __restrict__ rowbeg,
        const int* __restrict__ rowend,
        const int* __restrict__ csrc, const float* __restrict__ bias,
        __half* __restrict__ out) {
    int wid  = threadIdx.x >> 6;
    int lane = threadIdx.x & 63;
    int n = blockIdx.x * 4 + wid;
    int sub = lane >> 4;
    int c4  = lane & 15;
    int hd  = c4 >> 2;
    int beg = rowbeg[n], end = rowend[n];
    float sdh = sdst[n * NHEADS + hd];

    float4 acc = make_float4(0.f, 0.f, 0.f, 0.f);
    float z = 0.f;
    for (int cb = beg; cb < end; cb += 64) {
        int m = min(64, end - cb);
        int s_all = (cb + lane < end) ? csrc[cb + lane] : 0;
        for (int pb = 0; pb < m; pb += 16) {
            float ssv[4]; uint2 hr[4];
            #pragma unroll
            for (int o = 0; o < 4; o++) {
                int jj = pb + sub * 4 + o;
                int s = __shfl(s_all, jj);
                if (jj < m) {
                    ssv[o] = ssrc[s * NHEADS + hd];
                    hr[o] = *(const uint2*)(h + (size_t)s * HIDD + c4 * 4);
                }
            }
            #pragma unroll
            for (int o = 0; o < 4; o++) {
                int jj = pb + sub * 4 + o;
                if (jj < m) {
                    float eh = ssv[o] + sdh;
                    eh = eh > 0.f ? eh : 0.2f * eh;
                    float w = __expf(eh);
                    float2 lo = __half22float2(*(__half2*)&hr[o].x);
                    float2 hi = __half22float2(*(__half2*)&hr[o].y);
                    acc.x += lo.x * w; acc.y += lo.y * w;
                    acc.z += hi.x * w; acc.w += hi.y * w;
                    z += w;
                }
            }
        }
    }
    acc.x += __shfl_xor(acc.x, 16); acc.y += __shfl_xor(acc.y, 16);
    acc.z += __shfl_xor(acc.z, 16); acc.w += __shfl_xor(acc.w, 16);
    z += __shfl_xor(z, 16);
    acc.x += __shfl_xor(acc.x, 32); acc.y += __shfl_xor(acc.y, 32);
    acc.z += __shfl_xor(acc.z, 32); acc.w += __shfl_xor(acc.w, 32);
    z += __shfl_xor(z, 32);

    if (sub == 0) {
        float inv_z = 1.0f / (z + 1e-16f);
        float4 bv = *(const float4*)(bias + c4 * 4);
        float v0 = acc.x * inv_z + bv.x; v0 = v0 > 0.f ? v0 : 0.f;
        float v1 = acc.y * inv_z + bv.y; v1 = v1 > 0.f ? v1 : 0.f;
        float v2 = acc.z * inv_z + bv.z; v2 = v2 > 0.f ? v2 : 0.f;
        float v3 = acc.w * inv_z + bv.w; v3 = v3 > 0.f ? v3 : 0.f;
        union { __half2 h2[2]; uint2 u; } pk;
        pk.h2[0] = __floats2half2_rn(v0, v1);
        pk.h2[1] = __floats2half2_rn(v2, v3);
        *(uint2*)(out + (size_t)n * HIDD + c4 * 4) = pk.u;
    }
}

// ---------------- fused FC head via fdot2: 64-node tile ----------------

__global__ __launch_bounds__(256) void k_fc_fused(const __half* __restrict__ x,
        const unsigned* __restrict__ W1p, const float* __restrict__ b1,
        const unsigned* __restrict__ W2p, const float* __restrict__ b2,
        float* __restrict__ out) {
    __shared__ unsigned wl[5120];       // 20 KB
    __shared__ unsigned xt2[32][68];    // 8.7 KB
    __shared__ unsigned y2[80][68];     // 21.76 KB
    int t = threadIdx.x;
    int nb = blockIdx.x * 64;
    const uint4* wl4 = (const uint4*)wl;

    for (int i = t; i < 5120 / 4; i += 256)
        ((uint4*)wl)[i] = ((const uint4*)W1p)[i];
    #pragma unroll
    for (int r = 0; r < 4; r++) {
        int idx = t + r * 256;
        int node = idx & 63, kq = idx >> 6;
        int n = nb + node;
        uint2 v = make_uint2(0u, 0u);
        if (n < NN) v = ((const uint2*)(x + (size_t)n * 64))[kq];
        xt2[kq * 2 + 0][node] = v.x;
        xt2[kq * 2 + 1][node] = v.y;
    }
    __syncthreads();

    {
        int qg = t & 7, ng = t >> 3;
        float acc[2][5][4] = {};
        #pragma unroll 2
        for (int k2 = 0; k2 < 32; k2++) {
            uint2 xv = *(const uint2*)&xt2[k2][ng * 2];
            #pragma unroll
            for (int i = 0; i < 5; i++) {
                uint4 wv = wl4[k2 * 40 + qg + 8 * i];
                acc[0][i][0] = fdot2f(xv.x, wv.x, acc[0][i][0]);
                acc[0][i][1] = fdot2f(xv.x, wv.y, acc[0][i][1]);
                acc[0][i][2] = fdot2f(xv.x, wv.z, acc[0][i][2]);
                acc[0][i][3] = fdot2f(xv.x, wv.w, acc[0][i][3]);
                acc[1][i][0] = fdot2f(xv.y, wv.x, acc[1][i][0]);
                acc[1][i][1] = fdot2f(xv.y, wv.y, acc[1][i][1]);
                acc[1][i][2] = fdot2f(xv.y, wv.z, acc[1][i][2]);
                acc[1][i][3] = fdot2f(xv.y, wv.w, acc[1][i][3]);
            }
        }
        #pragma unroll
        for (int i = 0; i < 5; i++) {
            int j0 = (qg + 8 * i) * 4;
            float4 bv = *(const float4*)(b1 + j0);
            #pragma unroll
            for (int r = 0; r < 2; r++) {
                int node = ng * 2 + r;
                float v0 = acc[r][i][0] + bv.x; v0 = v0 > 0.f ? v0 : 0.f;
                float v1 = acc[r][i][1] + bv.y; v1 = v1 > 0.f ? v1 : 0.f;
                float v2 = acc[r][i][2] + bv.z; v2 = v2 > 0.f ? v2 : 0.f;
                float v3 = acc[r][i][3] + bv.w; v3 = v3 > 0.f ? v3 : 0.f;
                __half2 p0 = __floats2half2_rn(v0, v1);
                __half2 p1 = __floats2half2_rn(v2, v3);
                y2[(qg + 8 * i) * 2 + 0][node] = *(unsigned*)&p0;
                y2[(qg + 8 * i) * 2 + 1][node] = *(unsigned*)&p1;
            }
        }
    }
    __syncthreads();

    for (int i = t; i < 5120 / 4; i += 256)
        ((uint4*)wl)[i] = ((const uint4*)W2p)[i];
    __syncthreads();

    {
        int qg = t & 15, ng = t >> 4;
        float acc[4][4] = {};
        #pragma unroll 2
        for (int k2 = 0; k2 < 80; k2++) {
            uint4 wv = wl4[k2 * 16 + qg];
            uint4 yv = *(const uint4*)&y2[k2][ng * 4];
            acc[0][0] = fdot2f(yv.x, wv.x, acc[0][0]);
            acc[0][1] = fdot2f(yv.x, wv.y, acc[0][1]);
            acc[0][2] = fdot2f(yv.x, wv.z, acc[0][2]);
            acc[0][3] = fdot2f(yv.x, wv.w, acc[0][3]);
            acc[1][0] = fdot2f(yv.y, wv.x, acc[1][0]);
            acc[1][1] = fdot2f(yv.y, wv.y, acc[1][1]);
            acc[1][2] = fdot2f(yv.y, wv.z, acc[1][2]);
            acc[1][3] = fdot2f(yv.y, wv.w, acc[1][3]);
            acc[2][0] = fdot2f(yv.z, wv.x, acc[2][0]);
            acc[2][1] = fdot2f(yv.z, wv.y, acc[2][1]);
            acc[2][2] = fdot2f(yv.z, wv.z, acc[2][2]);
            acc[2][3] = fdot2f(yv.z, wv.w, acc[2][3]);
            acc[3][0] = fdot2f(yv.w, wv.x, acc[3][0]);
            acc[3][1] = fdot2f(yv.w, wv.y, acc[3][1]);
            acc[3][2] = fdot2f(yv.w, wv.z, acc[3][2]);
            acc[3][3] = fdot2f(yv.w, wv.w, acc[3][3]);
        }
        int j0 = qg * 4;
        float4 bv = *(const float4*)(b2 + j0);
        #pragma unroll
        for (int r = 0; r < 4; r++) {
            int n = nb + ng * 4 + r;
            if (n < NN) {
                float4 o;
                o.x = acc[r][0] + bv.x; o.y = acc[r][1] + bv.y;
                o.z = acc[r][2] + bv.z; o.w = acc[r][3] + bv.w;
                *(float4*)(out + (size_t)n * 64 + j0) = o;
            }
        }
    }
}

// ---------------- launch ----------------

extern "C" void kernel_launch(void* const* d_in, const int* in_sizes, int n_in,
                              void* d_out, int out_size, void* d_ws, size_t ws_size,
                              hipStream_t stream) {
    const float* x   = (const float*)d_in[0];
    const int*   ei  = (const int*)d_in[1];
    const float* W0  = (const float*)d_in[2];
    const float* as0 = (const float*)d_in[3];
    const float* ad0 = (const float*)d_in[4];
    const float* b0  = (const float*)d_in[5];
    const float* W1  = (const float*)d_in[6];
    const float* as1 = (const float*)d_in[7];
    const float* ad1 = (const float*)d_in[8];
    const float* b1  = (const float*)d_in[9];
    const float* W2  = (const float*)d_in[10];
    const float* as2 = (const float*)d_in[11];
    const float* ad2 = (const float*)d_in[12];
    const float* b2  = (const float*)d_in[13];
    const float* fw1 = (const float*)d_in[14];
    const float* fb1 = (const float*)d_in[15];
    const float* fw2 = (const float*)d_in[16];
    const float* fb2 = (const float*)d_in[17];

    float* ws = (float*)d_ws;
    __half* hA  = (__half*)ws;                       // N*64 halves = N*32 floats
    __half* hB  = (__half*)(ws + (size_t)NN * 32);   // N*32 floats
    float* sAsrc = ws + (size_t)NN * 64;             // N*4
    float* sAdst = sAsrc + (size_t)NN * NHEADS;      // N*4
    float* sBsrc = sAdst + (size_t)NN * NHEADS;      // N*4
    float* sBdst = sBsrc + (size_t)NN * NHEADS;      // N*4
    float* actf  = sBdst + (size_t)NN * NHEADS;      // N*32 floats (fp16 act)
    __half* act  = (__half*)actf;
    float* scr   = actf + (size_t)NN * 32;           // CSR scratch region
    unsigned* binned = (unsigned*)scr;               // NBKT*BSTRIDE ~1.0M
    int*   csrc   = (int*)scr + 1100000;             // NBKT*BSTRIDE ~1.0M
    int*   rowbeg = (int*)scr + 2200000;             // NN
    int*   rowend = (int*)scr + 2300000;             // NN
    int*   cursor = (int*)scr + 2400000;             // NBKT
    unsigned* W1p = (unsigned*)scr + 2410000;        // 5120
    unsigned* W2p = (unsigned*)scr + 2420000;        // 5120

    k_packw<<<20, 256, 0, stream>>>(fw1, fw2, W1p, W2p, cursor);
    k_binwrite<<<NEBLK, 256, 0, stream>>>(ei, cursor, binned);
    k_csr_final<<<NBKT, 256, 0, stream>>>(cursor, binned, rowbeg, rowend, csrc);

    // layer 0 GEMM: x @ W0 -> hA, sA
    k_gemm_scores<128><<<NGB, 256, 0, stream>>>(x, W0, as0, ad0, hA, sAsrc, sAdst);
    // fused: aggr(layer0) + gemm(layer1) -> hB, sB
    k_aggr_gemm<<<NGB, 512, 0, stream>>>(hA, sAsrc, sAdst, rowbeg, rowend, csrc,
                                         b0, W1, as1, ad1, hB, sBsrc, sBdst);
    // fused: aggr(layer1) + gemm(layer2) -> hA, sA
    k_aggr_gemm<<<NGB, 512, 0, stream>>>(hB, sBsrc, sBdst, rowbeg, rowend, csrc,
                                         b1, W2, as2, ad2, hA, sAsrc, sAdst);
    // final aggregation -> act (fp16)
    k_aggr<<<NN / 4, 256, 0, stream>>>(hA, sAsrc, sAdst, rowbeg, rowend, csrc, b2, act);

    // fused FC head (fdot2, packed fp16 weights)
    k_fc_fused<<<NGB, 256, 0, stream>>>(act, W1p, fb1, W2p, fb2, (float*)d_out);
}